// Round 23
// baseline (62.778 us; speedup 1.0000x reference)
//
#include <hip/hip_runtime.h>
#include <hip/hip_fp16.h>
#include <math.h>

#define BATCH 8
#define H 480
#define W 640
#define HW (H * W)

// ---- single-launch geometry (r15/r21): all 16 steps fused, 224 blocks ----
#define PS 16                 // fused steps (= total)
#define PTX 96                // output tile width
#define PTY 128               // output tile height
#define PRX 128               // region cols = PTX + 2*PS (= 64 lanes x 2)
#define PRY 160               // region rows
#define NT 1024               // 16 waves; wave = strip, lane = col pair
#define RPT 10                // rows per thread (held in registers)
#define NSTRIP 16
#define NBX 7
#define NBY 4
#define NBLK (NBX * NBY * BATCH)   // 224 = 8 XCDs x 28
#define NXCD 8
#define BPX (NBLK / NXCD)

// ---- async staging pipeline ----
#define DEPTH 2               // double-buffered chunk staging
#define RPC 5                 // rows per chunk (RPT/2)
#define CHUNKS 18             // 9 planes x 2 chunks

typedef __half2 h2;

__device__ __forceinline__ unsigned h2u(h2 v) { return __builtin_bit_cast(unsigned, v); }
__device__ __forceinline__ h2 u2h(unsigned u) { return __builtin_bit_cast(h2, u); }

// async global->LDS, 4 B/lane: lane i's 4 B land at ldsbase + i*4.
__device__ __forceinline__ void gld_lds(const float* g, float* l) {
    __builtin_amdgcn_global_load_lds(
        (const __attribute__((address_space(1))) void*)g,
        (__attribute__((address_space(3))) void*)l, 4, 0, 0);
}

// DPP wave-wide shifts; shifted-in lanes get 0 (rim: trapezoid-safe / w=0 px).
__device__ __forceinline__ h2 dppLh(h2 v) {
    return u2h((unsigned)__builtin_amdgcn_update_dpp(
        0, (int)h2u(v), 0x138, 0xF, 0xF, false));
}
__device__ __forceinline__ h2 dppRh(h2 v) {
    return u2h((unsigned)__builtin_amdgcn_update_dpp(
        0, (int)h2u(v), 0x130, 0xF, 0xF, false));
}
__device__ __forceinline__ h2 algn(h2 a, h2 b) {
    return u2h(__builtin_amdgcn_alignbit(h2u(a), h2u(b), 16));
}

struct Win { h2 L, C, R; };
__device__ __forceinline__ Win mkwin(h2 c) {
    Win w;
    w.C = c;
    w.L = algn(c, dppLh(c));
    w.R = algn(dppRh(c), c);
    return w;
}

// 9-tap packed update for one output row: 9 x v_pk_fma_f16.
__device__ __forceinline__ h2 rowpx(const h2* wt, h2 bias, Win T, Win M, Win B) {
    h2 a = bias;
    a = __hfma2(wt[0], T.L, a);
    a = __hfma2(wt[1], T.C, a);
    a = __hfma2(wt[2], T.R, a);
    a = __hfma2(wt[3], M.L, a);
    a = __hfma2(wt[4], M.C, a);
    a = __hfma2(wt[5], M.R, a);
    a = __hfma2(wt[6], B.L, a);
    a = __hfma2(wt[7], B.C, a);
    a = __hfma2(wt[8], B.R, a);
    return a;
}

// r22 structure + async-staged prologue: guided planes are DMA'd into a
// per-wave LDS region via global_load_lds (no VGPR destinations -> load
// concurrency is not register-clamped), double-buffered 5-row chunks with
// counted vmcnt(10) so chunk n+1's DMA overlaps chunk n's exp/pack. Each
// wave stages only its own rows -> no barriers in the pipeline. Row/col
// windows are clamped in-image (all DMA addresses valid); invalid pixels
// get zero weights at finalize. Jacobi loop / swizzle / writeout = r22.
__global__ __launch_bounds__(NT) void prop16_kernel(
    const float* __restrict__ guided,   // (B,9,H,W)
    const float* __restrict__ x,        // (B,1,H,W)
    const float* __restrict__ sparse,   // (B,1,H,W)
    float* __restrict__ xout)           // (B,1,H,W)
{
    __shared__ float stg[DEPTH][NSTRIP][RPC][PRX];   // 81,920 B
    __shared__ unsigned bnd[2][NSTRIP][2][64];       // 16,384 B

    const int tid  = threadIdx.x;
    const int lane = tid & 63;          // col pair (0..63)
    const int strip = tid >> 6;         // wave id = strip (0..15)
    const int r0 = strip * RPT;

    // XCD swizzle: slot -> logical block (bijective, 224 = 8 * 28)
    const int slot = blockIdx.x;
    const int lb = (slot & (NXCD - 1)) * BPX + (slot >> 3);
    const int b  = lb / (NBX * NBY);
    const int rem = lb - b * (NBX * NBY);
    const int by = rem / NBX;
    const int bx = rem - by * NBX;

    const int bx0 = bx * PTX, by0 = by * PTY;
    const int gx0 = bx0 - PS, gy0 = by0 - PS;
    const size_t ob = (size_t)b * HW;
    const int gx = gx0 + 2 * lane;
    const bool cok = (gx >= 0) && (gx < W);

    // clamped staging windows (always in-image; gx0 even -> dx even)
    const int cx0 = min(max(gx0, 0), W - PRX);
    const int dx  = gx0 - cx0;
    const float* gpl = guided + (size_t)b * 9 * HW + cx0;

    // ---- phase 0: x + sparse -> xr, bias, (1-mask) with validity folded ----
    h2 xr[RPT], bs[RPT];
    float mke[RPT], mko[RPT], se[RPT], so[RPT];
#pragma unroll
    for (int i = 0; i < RPT; ++i) {
        const int gy = gy0 + r0 + i;
        se[i] = 0.f; so[i] = 0.f;
        if (cok && gy >= 0 && gy < H) {
            const size_t p = ob + (size_t)gy * W + gx;
            const float2 xf = *(const float2*)(x + p);
            const float2 sv = *(const float2*)(sparse + p);
            const float me = (sv.x > 0.f) ? 1.f : 0.f;
            const float mo = (sv.y > 0.f) ? 1.f : 0.f;
            xr[i] = __floats2half2_rn(xf.x, xf.y);
            bs[i] = __floats2half2_rn(me * xf.x, mo * xf.y);
            mke[i] = 1.f - me; mko[i] = 1.f - mo;
        } else {
            xr[i] = __floats2half2_rn(0.f, 0.f);
            bs[i] = xr[i];
            mke[i] = 0.f; mko[i] = 0.f;
        }
    }
    // publish initial boundary rows (state 0 lives in bnd[0])
    bnd[0][strip][0][lane] = h2u(xr[0]);
    bnd[0][strip][1][lane] = h2u(xr[RPT - 1]);

    asm volatile("s_waitcnt vmcnt(0)" ::: "memory");   // clean vm counter

    // ---- async-staged softmax: 18 chunks, 2-deep pipeline, no barriers ----
    h2 wt[RPT][9];
#define ISSUE(c_) do {                                                       \
        const int k_ = (c_) >> 1, pb_ = ((c_) & 1) * RPC;                    \
        float* lb_ = &stg[(c_) % DEPTH][strip][0][0];                        \
        _Pragma("unroll")                                                    \
        for (int rr_ = 0; rr_ < RPC; ++rr_) {                                \
            const int gy_ = min(max(gy0 + r0 + pb_ + rr_, 0), H - 1);        \
            const float* gs_ = gpl + (size_t)k_ * HW + (size_t)gy_ * W;      \
            gld_lds(gs_ + lane,      lb_ + rr_ * PRX);                       \
            gld_lds(gs_ + 64 + lane, lb_ + rr_ * PRX + 64);                  \
        }                                                                    \
    } while (0)

    ISSUE(0);
    ISSUE(1);
    int ci = 2 * lane + dx;
    ci = min(max(ci, 0), PRX - 2);     // invalid lanes read safe garbage
#pragma unroll
    for (int c = 0; c < CHUNKS; ++c) {
        if (c < CHUNKS - 1) asm volatile("s_waitcnt vmcnt(10)" ::: "memory");
        else                asm volatile("s_waitcnt vmcnt(0)" ::: "memory");
        const int k = c >> 1, pb = (c & 1) * RPC;
        const float* lbc = &stg[c % DEPTH][strip][0][0];
#pragma unroll
        for (int rr = 0; rr < RPC; ++rr) {
            const float2 gv = *(const float2*)(lbc + rr * PRX + ci);
            const int i = pb + rr;
            const float ee = __expf(gv.x);
            const float eo = __expf(gv.y);
            se[i] += ee; so[i] += eo;
            wt[i][k] = __floats2half2_rn(ee, eo);
        }
        if (c + DEPTH < CHUNKS) ISSUE(c + DEPTH);
    }
#undef ISSUE

    // ---- finalize: fold (1-mask)/sum into the packed weights ----
#pragma unroll
    for (int i = 0; i < RPT; ++i) {
        const float sce = mke[i] * __builtin_amdgcn_rcpf(se[i]);
        const float sco = mko[i] * __builtin_amdgcn_rcpf(so[i]);
        const h2 sc = __floats2half2_rn(sce, sco);
#pragma unroll
        for (int k = 0; k < 9; ++k) wt[i][k] = __hmul2(wt[i][k], sc);
    }
    __syncthreads();     // bnd[0] visible to neighbor strips

    // ---- 16 Jacobi steps; interior in registers, boundaries via LDS ----
    for (int t = 0; t < PS; ++t) {
        const int cur = t & 1, nxt = cur ^ 1;
        h2 tp, bp;
        if (strip > 0) tp = u2h(bnd[cur][strip - 1][1][lane]);
        else           tp = xr[0];
        if (strip < NSTRIP - 1) bp = u2h(bnd[cur][strip + 1][0][lane]);
        else                    bp = xr[RPT - 1];
        Win T = mkwin(tp);
        Win M = mkwin(xr[0]);
        h2 nfirst;
#pragma unroll
        for (int r = 0; r < RPT; ++r) {
            const Win B = mkwin((r < RPT - 1) ? xr[r + 1] : bp);
            const h2 n = rowpx(wt[r], bs[r], T, M, B);
            if (r == 0) nfirst = n;
            xr[r] = n;
            T = M; M = B;
        }
        bnd[nxt][strip][0][lane] = h2u(nfirst);
        bnd[nxt][strip][1][lane] = h2u(xr[RPT - 1]);
        __syncthreads();
    }

    // ---- write own tile pixels straight from registers (f32 out) ----
    if ((2 * lane) >= PS && (2 * lane) < PS + PTX && gx < W) {
#pragma unroll
        for (int i = 0; i < RPT; ++i) {
            const int rr = r0 + i;
            const int gy = gy0 + rr;
            if (rr >= PS && rr < PS + PTY && gy < H) {
                const float2 o = __half22float2(xr[i]);
                *(float2*)(xout + ob + (size_t)gy * W + gx) = o;
            }
        }
    }
}

extern "C" void kernel_launch(void* const* d_in, const int* in_sizes, int n_in,
                              void* d_out, int out_size, void* d_ws, size_t ws_size,
                              hipStream_t stream) {
    const float* guided = (const float*)d_in[0];
    const float* x      = (const float*)d_in[1];
    const float* sparse = (const float*)d_in[2];
    float* out = (float*)d_out;

    dim3 blk(NT, 1, 1);
    dim3 grd(NBLK, 1, 1);   // 224 blocks, 1D for explicit XCD swizzle
    prop16_kernel<<<grd, blk, 0, stream>>>(guided, x, sparse, out);
}